// Round 11
// baseline (215.995 us; speedup 1.0000x reference)
//
#include <hip/hip_runtime.h>
#include <hip/hip_bf16.h>
#include <math.h>

typedef unsigned short ushort_t;
typedef unsigned char uchar_t;
typedef unsigned int uint_t;
typedef __attribute__((ext_vector_type(8))) short bf16x8;   // 8 bf16 = 4 VGPRs
typedef __attribute__((ext_vector_type(4))) float f32x4;
typedef __attribute__((ext_vector_type(2))) long longx2;    // 16 B = {ksub0, ksub1} fp8 frags

#define AS1 __attribute__((address_space(1)))
#define AS3 __attribute__((address_space(3)))

__device__ __forceinline__ void gld_lds16(const void* g, void* l) {
  // async global->LDS, 16B per lane; LDS dest = wave-uniform base + lane*16
  __builtin_amdgcn_global_load_lds((const AS1 void*)g, (AS3 void*)l, 16, 0, 0);
}

__device__ __forceinline__ ushort_t f32_to_bf16_bits(float v) {
  __hip_bfloat16 b = __float2bfloat16(v);
  return *(ushort_t*)&b;
}

__device__ __forceinline__ uint_t pack_fp8x4(float4 v, float sc) {
  int r = __builtin_amdgcn_cvt_pk_fp8_f32(v.x * sc, v.y * sc, 0, false);
  r = __builtin_amdgcn_cvt_pk_fp8_f32(v.z * sc, v.w * sc, r, true);
  return (uint_t)r;
}

// ================= tiled operand layout =================
// Unit tile = 16 rows x 64 B, stored contiguously (1024 B). Tile index =
// rowblock * nKtiles + kt. Within a tile row rl, the 64 B is split into 16-B
// units XOR-permuted by a per-row key so MFMA fragment ds_read_b128 are
// conflict-free:
//   bf16: unit u = k[16u..16u+16);      phys = u ^ ((rl>>1)&3)
//   fp8 : unit u = {ksub0 k[8u..8u+8) | ksub1 k[32+8u..+8)};  phys = u ^ ((rl>>1)&3)
// (fp8 pairs the two ksub fragments adjacently so one b128 feeds both MFMAs —
//  R2-verified end-to-end.)  global_load_lds copies tiles verbatim.

// ---------------- single prep kernel ----------------
__global__ __launch_bounds__(256) void prep(const float4* __restrict__ h,
                                            uchar_t* __restrict__ h8, int rowsH,
                                            const float4* __restrict__ p,
                                            uchar_t* __restrict__ p8, int rowsP,
                                            const float* __restrict__ pc,
                                            ushort_t* __restrict__ pcT,
                                            int P, int C, int normBlocks) {
  __shared__ float tile[32][33];
  if ((int)blockIdx.x < normBlocks) {
    int r = (blockIdx.x * 256 + threadIdx.x) >> 6;
    const int lane = threadIdx.x & 63;
    const float4* xr;
    uchar_t* o8;
    if (r < rowsH) {
      xr = h + (size_t)r * 192;          // 768 floats = 192 float4
      o8 = h8;
    } else {
      r -= rowsH;
      if (r >= rowsP) return;
      xr = p + (size_t)r * 192;
      o8 = p8;
    }
    float4 v0 = xr[lane];
    float4 v1 = xr[lane + 64];
    float4 v2 = xr[lane + 128];
    float ss = v0.x * v0.x + v0.y * v0.y + v0.z * v0.z + v0.w * v0.w
             + v1.x * v1.x + v1.y * v1.y + v1.z * v1.z + v1.w * v1.w
             + v2.x * v2.x + v2.y * v2.y + v2.z * v2.z + v2.w * v2.w;
#pragma unroll
    for (int off = 32; off > 0; off >>= 1) ss += __shfl_xor(ss, off, 64);
    const float sc = 4.0f / fmaxf(sqrtf(ss), 1e-12f);
    // lane L holds k-local = 4*(L&15)+{0..3} of tile ktb = L>>4 in each 256-group.
    // fp8 paired-unit layout (R2-verified): u=(L&7)>>1, ksub=(L&15)>>3, inner=4*(L&1)
    const int rb = r >> 4, rl = r & 15;
    const int key4 = (rl >> 1) & 3;
    const int u = (lane & 7) >> 1;
    const int ksub = (lane & 15) >> 3;
    const int cphys = ((u ^ key4) << 4) + (ksub << 3) + ((lane & 1) << 2);
    const int ktb = lane >> 4;                        // tile within group
    uchar_t* rowbase = o8 + (size_t)rb * 12 * 1024 + rl * 64 + cphys;
    *(uint_t*)(rowbase + (size_t)(ktb) * 1024)     = pack_fp8x4(v0, sc);
    *(uint_t*)(rowbase + (size_t)(4 + ktb) * 1024) = pack_fp8x4(v1, sc);
    *(uint_t*)(rowbase + (size_t)(8 + ktb) * 1024) = pack_fp8x4(v2, sc);
  } else {
    const int b = blockIdx.x - normBlocks;
    const int nkb = P / 32;                   // k-tiles per pcT row-block (=64)
    const int bk = b % nkb, bc = b / nkb;
    const int k0 = bk * 32, c0 = bc * 32;
    const int tx = threadIdx.x & 31, ty = threadIdx.x >> 5;   // ty 0..7
#pragma unroll
    for (int rr = 0; rr < 4; ++rr) {
      const int c = c0 + tx;
      tile[ty + rr * 8][tx] = (c < C) ? pc[(size_t)(k0 + ty + rr * 8) * C + c] : 0.f;
    }
    __syncthreads();
    const int c2 = tx >> 3, off = tx & 7;
#pragma unroll
    for (int rr = 0; rr < 4; ++rr) {
      const int row = c0 + ty + rr * 8;       // pcT row (class dim)
      const int rb = row >> 4, rl = row & 15;
      const int key4 = (rl >> 1) & 3;
      size_t us = (((size_t)rb * nkb + bk) * 16 + rl) * 32 + ((c2 ^ key4) << 3) + off;
      pcT[us] = f32_to_bf16_bits(tile[tx][ty + rr * 8]);
    }
  }
}

// ======== shared schedule primitives (t3 skeleton, R9/R10-verified; 1-barrier variant R11) ========
#define BARRIER() do { asm volatile("" ::: "memory"); __builtin_amdgcn_s_barrier(); \
                       asm volatile("" ::: "memory"); } while (0)
#define VM3()     asm volatile("s_waitcnt vmcnt(3)" ::: "memory")
#define VM0()     asm volatile("s_waitcnt vmcnt(0)" ::: "memory")
#define PRIO1()   __builtin_amdgcn_s_setprio(1)
#define PRIO0()   __builtin_amdgcn_s_setprio(0)
#define MM(a, b, c)  __builtin_amdgcn_mfma_f32_16x16x32_bf16(a, b, c, 0, 0, 0)
#define MM8(a, b, c) __builtin_amdgcn_mfma_f32_16x16x32_fp8_fp8(a, b, c, 0, 0, 0)

// ---- 1-barrier t3 loop (R11 change): {reads (plain C, compiler lgkm waits) | stage(kt+2)
//   | MFMA (data-dep ordered) | vmcnt gate | BARRIER}.  The old mid-BARRIER+LGKM0 forced a
//   block-wide LDS drain before any MFMA (convoy).  Proof of safety without it:
//   (a) every wave's 8 reads of tile kt are consumed by its MFMAs -> compiler lgkm waits
//       drain them before that wave reaches barrier(kt);
//   (b) a stage into that buffer (tile kt+3 at iteration kt+1) is issued only by waves
//       that passed barrier(kt) -> no cross-wave WAR;
//   (c) VM3 at kt (own counter; stages are wave-private calls) leaves only tile-(kt+2)'s
//       3 calls -> tile kt+1 landed; the barrier makes it visible to all waves;
//   (d) barriers unconditional; tails unchanged (VM0 at nKt-2, none at nKt-1).

// ---------------- GEMM1: 128x256 fp8, BK=64, TRIPLE-buffered, 2 blocks/CU ----------------
__launch_bounds__(512, 4)
__global__ void gemm1_fp8_t3(const uchar_t* __restrict__ A, const uchar_t* __restrict__ B,
                             ushort_t* __restrict__ act, const float* __restrict__ tptr,
                             int nKt, int actKT, int gx, int gxlog2) {
  __shared__ __align__(16) uchar_t sm1[73728];   // 3 x (A 8K + B 16K)
  const int tid = threadIdx.x, lane = tid & 63, wave = tid >> 6;   // 8 waves
  const int wm = wave >> 2, wn = wave & 3;                         // 2M x 4N, 64x64 each
  const int lid = blockIdx.x, xcd = lid & 7, q = lid >> 3;
  const int tb = q & (gx - 1), sb = ((q >> gxlog2) << 3) | xcd;    // 8 x 128 grid

  f32x4 acc[4][4];
#pragma unroll
  for (int i = 0; i < 4; ++i)
#pragma unroll
    for (int j = 0; j < 4; ++j) acc[i][j] = (f32x4){0.f, 0.f, 0.f, 0.f};

  const uchar_t* Apl = A + (((size_t)(sb * 8) * nKt) << 10) + lane * 16;
  const uchar_t* Bpl = B + (((size_t)(tb * 16) * nKt) << 10) + lane * 16;

  // per-lane fragment offset within a unit tile (16-B unit XOR key)
  const int fr = lane & 15, g = lane >> 4;
  const int rdoff = fr * 64 + ((g ^ ((fr >> 1) & 3)) << 4);
  const uchar_t* smA = sm1 + (wm << 12) + rdoff;          // + buf offset at use
  const uchar_t* smB = sm1 + 8192 + (wn << 12) + rdoff;

  // stage roles (3 calls/wave/K-tile): wave w stages A tile {w}, B tiles {w, w+8}
#define G1_STA(r_, T_, bo_) gld_lds16(Apl + ((size_t)((r_) * nKt + (T_)) << 10), \
                                      sm1 + (bo_) + ((r_) << 10))
#define G1_STB(c_, T_, bo_) gld_lds16(Bpl + ((size_t)((c_) * nKt + (T_)) << 10), \
                                      sm1 + (bo_) + 8192 + ((c_) << 10))
#define G1_DSA(bo_, i_) (*(const longx2*)(smA + (bo_) + ((i_) << 10)))
#define G1_DSB(bo_, j_) (*(const longx2*)(smB + (bo_) + ((j_) << 10)))

  // prologue: tile 0 (oldest 3), tile 1 (3); VM3 drains tile 0
  G1_STA(wave, 0, 0); G1_STB(wave, 0, 0); G1_STB(wave + 8, 0, 0);
  G1_STA(wave, 1, 24576); G1_STB(wave, 1, 24576); G1_STB(wave + 8, 1, 24576);
  VM3(); BARRIER();

  int boC = 0, boN = 24576, boNN = 49152;
  for (int kt = 0; kt < nKt; ++kt) {
    longx2 a0 = G1_DSA(boC, 0), a1 = G1_DSA(boC, 1), a2 = G1_DSA(boC, 2), a3 = G1_DSA(boC, 3);
    longx2 b0 = G1_DSB(boC, 0), b1 = G1_DSB(boC, 1), b2 = G1_DSB(boC, 2), b3 = G1_DSB(boC, 3);
    if (kt + 2 < nKt) {
      G1_STA(wave, kt + 2, boNN); G1_STB(wave, kt + 2, boNN); G1_STB(wave + 8, kt + 2, boNN);
    }
    PRIO1();
    // ksub0 (K 0..31)
    acc[0][0] = MM8(a0[0], b0[0], acc[0][0]); acc[0][1] = MM8(a0[0], b1[0], acc[0][1]);
    acc[0][2] = MM8(a0[0], b2[0], acc[0][2]); acc[0][3] = MM8(a0[0], b3[0], acc[0][3]);
    acc[1][0] = MM8(a1[0], b0[0], acc[1][0]); acc[1][1] = MM8(a1[0], b1[0], acc[1][1]);
    acc[1][2] = MM8(a1[0], b2[0], acc[1][2]); acc[1][3] = MM8(a1[0], b3[0], acc[1][3]);
    acc[2][0] = MM8(a2[0], b0[0], acc[2][0]); acc[2][1] = MM8(a2[0], b1[0], acc[2][1]);
    acc[2][2] = MM8(a2[0], b2[0], acc[2][2]); acc[2][3] = MM8(a2[0], b3[0], acc[2][3]);
    acc[3][0] = MM8(a3[0], b0[0], acc[3][0]); acc[3][1] = MM8(a3[0], b1[0], acc[3][1]);
    acc[3][2] = MM8(a3[0], b2[0], acc[3][2]); acc[3][3] = MM8(a3[0], b3[0], acc[3][3]);
    // ksub1 (K 32..63) — same acc re-touched at distance 16
    acc[0][0] = MM8(a0[1], b0[1], acc[0][0]); acc[0][1] = MM8(a0[1], b1[1], acc[0][1]);
    acc[0][2] = MM8(a0[1], b2[1], acc[0][2]); acc[0][3] = MM8(a0[1], b3[1], acc[0][3]);
    acc[1][0] = MM8(a1[1], b0[1], acc[1][0]); acc[1][1] = MM8(a1[1], b1[1], acc[1][1]);
    acc[1][2] = MM8(a1[1], b2[1], acc[1][2]); acc[1][3] = MM8(a1[1], b3[1], acc[1][3]);
    acc[2][0] = MM8(a2[1], b0[1], acc[2][0]); acc[2][1] = MM8(a2[1], b1[1], acc[2][1]);
    acc[2][2] = MM8(a2[1], b2[1], acc[2][2]); acc[2][3] = MM8(a2[1], b3[1], acc[2][3]);
    acc[3][0] = MM8(a3[1], b0[1], acc[3][0]); acc[3][1] = MM8(a3[1], b1[1], acc[3][1]);
    acc[3][2] = MM8(a3[1], b2[1], acc[3][2]); acc[3][3] = MM8(a3[1], b3[1], acc[3][3]);
    PRIO0();
    if (kt + 2 < nKt) { VM3(); } else if (kt + 1 < nKt) { VM0(); }
    BARRIER();
    int tswap = boC; boC = boN; boN = boNN; boNN = tswap;
  }

  float tmp = *tptr;
  const float tau = log1pf(expf(tmp));
  // C/D layout: col = lane&15, row = (lane>>4)*4 + reg   [measured m89/m91]
  const int crow = g * 4;
  const int rowB = sb * 128 + wm * 64, colB = tb * 256 + wn * 64;
#pragma unroll
  for (int i = 0; i < 4; ++i)
#pragma unroll
    for (int j = 0; j < 4; ++j) {
      const int col = colB + j * 16 + fr;
      const size_t ktile = col >> 5;
      const int c2 = (col >> 3) & 3, co = col & 7;
#pragma unroll
      for (int rr = 0; rr < 4; ++rr) {
        const int row = rowB + i * 16 + crow + rr;
        const int rb = row >> 4, rl = row & 15;
        const int key4 = (rl >> 1) & 3;
        float d2 = fmaxf(2.0f - acc[i][j][rr] * 0.125f, 0.0f);   // acc = 16*dot
        float d = d2 * rsqrtf(fmaxf(d2, 1e-20f));
        float a = __expf(-tau * d);
        act[(((size_t)rb * actKT + ktile) * 16 + rl) * 32 + ((c2 ^ key4) << 3) + co] =
            f32_to_bf16_bits(a);
      }
    }
}

// ---------------- GEMM2: 128x256 bf16, BK=32, TRIPLE-buffered, 2 blocks/CU ----------------
// R9/R10-verified at 60.7-62 us with mid-barrier; R11: 1-barrier loop (see proof above).
__launch_bounds__(512, 4)
__global__ void gemm2_bf16_t3(const ushort_t* __restrict__ A,
                              const ushort_t* __restrict__ B,
                              float* __restrict__ out, int ldc, int ncols,
                              int nKt) {
  __shared__ __align__(16) uchar_t sm[73728];   // 3 x (A 8K + B 16K)
  const int tid = threadIdx.x, lane = tid & 63, wave = tid >> 6;   // 8 waves
  const int wm = wave >> 2, wn = wave & 3;                         // 2M x 4N, 64x64 each
  const int lid = blockIdx.x, xcd = lid & 7, q = lid >> 3;
  const int tb = q & 3, sb = ((q >> 2) << 3) | xcd;   // col-tile 0..3, row-tile 0..127

  f32x4 acc[4][4];
#pragma unroll
  for (int i = 0; i < 4; ++i)
#pragma unroll
    for (int j = 0; j < 4; ++j) acc[i][j] = (f32x4){0.f, 0.f, 0.f, 0.f};

  const uchar_t* Apl = (const uchar_t*)A + (((size_t)(sb * 8) * nKt) << 10) + lane * 16;
  const uchar_t* Bpl = (const uchar_t*)B + (((size_t)(tb * 16) * nKt) << 10) + lane * 16;

  const int fr = lane & 15, g = lane >> 4;
  const int rdoff = fr * 64 + ((g ^ ((fr >> 1) & 3)) << 4);
  const uchar_t* smA = sm + (wm << 12) + rdoff;
  const uchar_t* smB = sm + 8192 + (wn << 12) + rdoff;

#define T3_STA(r_, T_, bo_) gld_lds16(Apl + ((size_t)((r_) * nKt + (T_)) << 10), \
                                      sm + (bo_) + ((r_) << 10))
#define T3_STB(c_, T_, bo_) gld_lds16(Bpl + ((size_t)((c_) * nKt + (T_)) << 10), \
                                      sm + (bo_) + 8192 + ((c_) << 10))
#define T3_DSA(bo_, i_) (*(const bf16x8*)(smA + (bo_) + ((i_) << 10)))
#define T3_DSB(bo_, j_) (*(const bf16x8*)(smB + (bo_) + ((j_) << 10)))

  T3_STA(wave, 0, 0); T3_STB(wave, 0, 0); T3_STB(wave + 8, 0, 0);
  T3_STA(wave, 1, 24576); T3_STB(wave, 1, 24576); T3_STB(wave + 8, 1, 24576);
  VM3(); BARRIER();

  int boC = 0, boN = 24576, boNN = 49152;
  for (int kt = 0; kt < nKt; ++kt) {
    bf16x8 a0 = T3_DSA(boC, 0), a1 = T3_DSA(boC, 1), a2 = T3_DSA(boC, 2), a3 = T3_DSA(boC, 3);
    bf16x8 b0 = T3_DSB(boC, 0), b1 = T3_DSB(boC, 1), b2 = T3_DSB(boC, 2), b3 = T3_DSB(boC, 3);
    if (kt + 2 < nKt) {
      T3_STA(wave, kt + 2, boNN); T3_STB(wave, kt + 2, boNN); T3_STB(wave + 8, kt + 2, boNN);
    }
    PRIO1();
    acc[0][0] = MM(a0, b0, acc[0][0]); acc[0][1] = MM(a0, b1, acc[0][1]);
    acc[0][2] = MM(a0, b2, acc[0][2]); acc[0][3] = MM(a0, b3, acc[0][3]);
    acc[1][0] = MM(a1, b0, acc[1][0]); acc[1][1] = MM(a1, b1, acc[1][1]);
    acc[1][2] = MM(a1, b2, acc[1][2]); acc[1][3] = MM(a1, b3, acc[1][3]);
    acc[2][0] = MM(a2, b0, acc[2][0]); acc[2][1] = MM(a2, b1, acc[2][1]);
    acc[2][2] = MM(a2, b2, acc[2][2]); acc[2][3] = MM(a2, b3, acc[2][3]);
    acc[3][0] = MM(a3, b0, acc[3][0]); acc[3][1] = MM(a3, b1, acc[3][1]);
    acc[3][2] = MM(a3, b2, acc[3][2]); acc[3][3] = MM(a3, b3, acc[3][3]);
    PRIO0();
    if (kt + 2 < nKt) { VM3(); } else if (kt + 1 < nKt) { VM0(); }
    BARRIER();
    int tswap = boC; boC = boN; boN = boNN; boNN = tswap;
  }

  // epilogue: C/D layout col = lane&15, row = (lane>>4)*4 + reg
  const int crow = g * 4;
  const int rowB = sb * 128 + wm * 64, colB = tb * 256 + wn * 64;
#pragma unroll
  for (int i = 0; i < 4; ++i)
#pragma unroll
    for (int j = 0; j < 4; ++j) {
      const int col = colB + j * 16 + fr;
      if (col < ncols) {
#pragma unroll
        for (int rr = 0; rr < 4; ++rr)
          out[(size_t)(rowB + i * 16 + crow + rr) * ldc + col] = acc[i][j][rr];
      }
    }
}

extern "C" void kernel_launch(void* const* d_in, const int* in_sizes, int n_in,
                              void* d_out, int out_size, void* d_ws, size_t ws_size,
                              hipStream_t stream) {
  const float* h    = (const float*)d_in[0];
  const float* prot = (const float*)d_in[1];
  const float* pc   = (const float*)d_in[2];
  const float* temp = (const float*)d_in[3];
  float* out = (float*)d_out;

  const int D = 768;
  const int N = in_sizes[0] / D;          // 16384
  const int P = in_sizes[1] / D;          // 2048
  const int C = in_sizes[2] / P;          // 1000
  const int CP = (C + 127) & ~127;        // 1024 (padded)

  // workspace layout (16B aligned), all tiled
  char* ws = (char*)d_ws;
  size_t off = 0;
  uchar_t* h8   = (uchar_t*)(ws + off); off += (size_t)N * D;         // 12.6 MB fp8
  uchar_t* p8   = (uchar_t*)(ws + off); off += (size_t)P * D;         //  1.6 MB fp8
  ushort_t* pcT = (ushort_t*)(ws + off); off += (size_t)CP * P * 2;   //  4.2 MB bf16
  ushort_t* act = (ushort_t*)(ws + off); off += (size_t)N * P * 2;    // 67.1 MB bf16
  (void)ws_size;  // total ~85.5 MB

  // single prep dispatch: normalize (fp8 x4, paired-unit tiled) + transpose (bf16, tiled)
  const int normBlocks = (N + P) / 4;                 // 4608
  const int transBlocks = (P / 32) * (CP / 32);       // 2048
  prep<<<normBlocks + transBlocks, 256, 0, stream>>>(
      (const float4*)h, h8, N, (const float4*)prot, p8, P,
      pc, pcT, P, C, normBlocks);

  // GEMM1: act[N,P](bf16 tiled) = epilogue(h8 @ p8^T), fp8, 128x256 BK=64 t3, 2 blocks/CU
  {
    const int GX = P / 256, GY = N / 128;   // 8, 128 -> 1024 blocks
    gemm1_fp8_t3<<<GX * GY, 512, 0, stream>>>(h8, p8, act, temp, D / 64, P / 32, GX, 3);
  }
  // GEMM2: out[N,C](f32) = act @ pcT^T, bf16, 128x256 BK=32 triple-buffer, 2 blocks/CU
  {
    const int GX = CP / 256, GY = N / 128;  // 4, 128 -> 512 blocks = 2/CU
    gemm2_bf16_t3<<<GX * GY, 512, 0, stream>>>(act, pcT, out, C, C, P / 32);
  }
}

// Round 12
// 209.473 us; speedup vs baseline: 1.0311x; 1.0311x over previous
//
#include <hip/hip_runtime.h>
#include <hip/hip_bf16.h>
#include <math.h>

typedef unsigned short ushort_t;
typedef unsigned char uchar_t;
typedef unsigned int uint_t;
typedef __attribute__((ext_vector_type(8))) short bf16x8;   // 8 bf16 = 4 VGPRs
typedef __attribute__((ext_vector_type(4))) float f32x4;
typedef __attribute__((ext_vector_type(2))) long longx2;    // 16 B = {ksub0, ksub1} fp8 frags

#define AS1 __attribute__((address_space(1)))
#define AS3 __attribute__((address_space(3)))

__device__ __forceinline__ void gld_lds16(const void* g, void* l) {
  // async global->LDS, 16B per lane; LDS dest = wave-uniform base + lane*16
  __builtin_amdgcn_global_load_lds((const AS1 void*)g, (AS3 void*)l, 16, 0, 0);
}

__device__ __forceinline__ ushort_t f32_to_bf16_bits(float v) {
  __hip_bfloat16 b = __float2bfloat16(v);
  return *(ushort_t*)&b;
}

__device__ __forceinline__ uint_t pack_fp8x4(float4 v, float sc) {
  int r = __builtin_amdgcn_cvt_pk_fp8_f32(v.x * sc, v.y * sc, 0, false);
  r = __builtin_amdgcn_cvt_pk_fp8_f32(v.z * sc, v.w * sc, r, true);
  return (uint_t)r;
}

// ================= tiled operand layout =================
// Unit tile = 16 rows x 64 B, stored contiguously (1024 B). Tile index =
// rowblock * nKtiles + kt. Within a tile row rl, the 64 B is split into 16-B
// units XOR-permuted by a per-row key so MFMA fragment ds_read_b128 are
// conflict-free:
//   bf16: unit u = k[16u..16u+16);      phys = u ^ ((rl>>1)&3)
//   fp8 : unit u = {ksub0 k[8u..8u+8) | ksub1 k[32+8u..+8)};  phys = u ^ ((rl>>1)&3)
// (fp8 pairs the two ksub fragments adjacently so one b128 feeds both MFMAs —
//  R2-verified end-to-end.)  global_load_lds copies tiles verbatim.

// ---------------- single prep kernel ----------------
__global__ __launch_bounds__(256) void prep(const float4* __restrict__ h,
                                            uchar_t* __restrict__ h8, int rowsH,
                                            const float4* __restrict__ p,
                                            uchar_t* __restrict__ p8, int rowsP,
                                            const float* __restrict__ pc,
                                            ushort_t* __restrict__ pcT,
                                            int P, int C, int normBlocks) {
  __shared__ float tile[32][33];
  if ((int)blockIdx.x < normBlocks) {
    int r = (blockIdx.x * 256 + threadIdx.x) >> 6;
    const int lane = threadIdx.x & 63;
    const float4* xr;
    uchar_t* o8;
    if (r < rowsH) {
      xr = h + (size_t)r * 192;          // 768 floats = 192 float4
      o8 = h8;
    } else {
      r -= rowsH;
      if (r >= rowsP) return;
      xr = p + (size_t)r * 192;
      o8 = p8;
    }
    float4 v0 = xr[lane];
    float4 v1 = xr[lane + 64];
    float4 v2 = xr[lane + 128];
    float ss = v0.x * v0.x + v0.y * v0.y + v0.z * v0.z + v0.w * v0.w
             + v1.x * v1.x + v1.y * v1.y + v1.z * v1.z + v1.w * v1.w
             + v2.x * v2.x + v2.y * v2.y + v2.z * v2.z + v2.w * v2.w;
#pragma unroll
    for (int off = 32; off > 0; off >>= 1) ss += __shfl_xor(ss, off, 64);
    const float sc = 4.0f / fmaxf(sqrtf(ss), 1e-12f);
    // lane L holds k-local = 4*(L&15)+{0..3} of tile ktb = L>>4 in each 256-group.
    // fp8 paired-unit layout (R2-verified): u=(L&7)>>1, ksub=(L&15)>>3, inner=4*(L&1)
    const int rb = r >> 4, rl = r & 15;
    const int key4 = (rl >> 1) & 3;
    const int u = (lane & 7) >> 1;
    const int ksub = (lane & 15) >> 3;
    const int cphys = ((u ^ key4) << 4) + (ksub << 3) + ((lane & 1) << 2);
    const int ktb = lane >> 4;                        // tile within group
    uchar_t* rowbase = o8 + (size_t)rb * 12 * 1024 + rl * 64 + cphys;
    *(uint_t*)(rowbase + (size_t)(ktb) * 1024)     = pack_fp8x4(v0, sc);
    *(uint_t*)(rowbase + (size_t)(4 + ktb) * 1024) = pack_fp8x4(v1, sc);
    *(uint_t*)(rowbase + (size_t)(8 + ktb) * 1024) = pack_fp8x4(v2, sc);
  } else {
    const int b = blockIdx.x - normBlocks;
    const int nkb = P / 32;                   // k-tiles per pcT row-block (=64)
    const int bk = b % nkb, bc = b / nkb;
    const int k0 = bk * 32, c0 = bc * 32;
    const int tx = threadIdx.x & 31, ty = threadIdx.x >> 5;   // ty 0..7
#pragma unroll
    for (int rr = 0; rr < 4; ++rr) {
      const int c = c0 + tx;
      tile[ty + rr * 8][tx] = (c < C) ? pc[(size_t)(k0 + ty + rr * 8) * C + c] : 0.f;
    }
    __syncthreads();
    const int c2 = tx >> 3, off = tx & 7;
#pragma unroll
    for (int rr = 0; rr < 4; ++rr) {
      const int row = c0 + ty + rr * 8;       // pcT row (class dim)
      const int rb = row >> 4, rl = row & 15;
      const int key4 = (rl >> 1) & 3;
      size_t us = (((size_t)rb * nkb + bk) * 16 + rl) * 32 + ((c2 ^ key4) << 3) + off;
      pcT[us] = f32_to_bf16_bits(tile[tx][ty + rr * 8]);
    }
  }
}

// ======== shared schedule primitives ========
#define BARRIER() do { asm volatile("" ::: "memory"); __builtin_amdgcn_s_barrier(); \
                       asm volatile("" ::: "memory"); } while (0)
#define LGKM0()   asm volatile("s_waitcnt lgkmcnt(0)" ::: "memory")
#define VM6()     asm volatile("s_waitcnt vmcnt(6)" ::: "memory")
#define VM3()     asm volatile("s_waitcnt vmcnt(3)" ::: "memory")
#define VM0()     asm volatile("s_waitcnt vmcnt(0)" ::: "memory")
#define PRIO1()   __builtin_amdgcn_s_setprio(1)
#define PRIO0()   __builtin_amdgcn_s_setprio(0)
#define MM(a, b, c)  __builtin_amdgcn_mfma_f32_16x16x32_bf16(a, b, c, 0, 0, 0)
#define MM8(a, b, c) __builtin_amdgcn_mfma_f32_16x16x32_fp8_fp8(a, b, c, 0, 0, 0)

// ---------------- GEMM1: 128x256 fp8, BK=64, t3, 1-barrier (R11-verified; helped short-K) ----------------
__launch_bounds__(512, 4)
__global__ void gemm1_fp8_t3(const uchar_t* __restrict__ A, const uchar_t* __restrict__ B,
                             ushort_t* __restrict__ act, const float* __restrict__ tptr,
                             int nKt, int actKT, int gx, int gxlog2) {
  __shared__ __align__(16) uchar_t sm1[73728];   // 3 x (A 8K + B 16K)
  const int tid = threadIdx.x, lane = tid & 63, wave = tid >> 6;   // 8 waves
  const int wm = wave >> 2, wn = wave & 3;                         // 2M x 4N, 64x64 each
  const int lid = blockIdx.x, xcd = lid & 7, q = lid >> 3;
  const int tb = q & (gx - 1), sb = ((q >> gxlog2) << 3) | xcd;    // 8 x 128 grid

  f32x4 acc[4][4];
#pragma unroll
  for (int i = 0; i < 4; ++i)
#pragma unroll
    for (int j = 0; j < 4; ++j) acc[i][j] = (f32x4){0.f, 0.f, 0.f, 0.f};

  const uchar_t* Apl = A + (((size_t)(sb * 8) * nKt) << 10) + lane * 16;
  const uchar_t* Bpl = B + (((size_t)(tb * 16) * nKt) << 10) + lane * 16;

  // per-lane fragment offset within a unit tile (16-B unit XOR key)
  const int fr = lane & 15, g = lane >> 4;
  const int rdoff = fr * 64 + ((g ^ ((fr >> 1) & 3)) << 4);
  const uchar_t* smA = sm1 + (wm << 12) + rdoff;          // + buf offset at use
  const uchar_t* smB = sm1 + 8192 + (wn << 12) + rdoff;

  // stage roles (3 calls/wave/K-tile): wave w stages A tile {w}, B tiles {w, w+8}
#define G1_STA(r_, T_, bo_) gld_lds16(Apl + ((size_t)((r_) * nKt + (T_)) << 10), \
                                      sm1 + (bo_) + ((r_) << 10))
#define G1_STB(c_, T_, bo_) gld_lds16(Bpl + ((size_t)((c_) * nKt + (T_)) << 10), \
                                      sm1 + (bo_) + 8192 + ((c_) << 10))
#define G1_DSA(bo_, i_) (*(const longx2*)(smA + (bo_) + ((i_) << 10)))
#define G1_DSB(bo_, j_) (*(const longx2*)(smB + (bo_) + ((j_) << 10)))

  // prologue: tile 0 (oldest 3), tile 1 (3); VM3 drains tile 0
  G1_STA(wave, 0, 0); G1_STB(wave, 0, 0); G1_STB(wave + 8, 0, 0);
  G1_STA(wave, 1, 24576); G1_STB(wave, 1, 24576); G1_STB(wave + 8, 1, 24576);
  VM3(); BARRIER();

  int boC = 0, boN = 24576, boNN = 49152;
  for (int kt = 0; kt < nKt; ++kt) {
    longx2 a0 = G1_DSA(boC, 0), a1 = G1_DSA(boC, 1), a2 = G1_DSA(boC, 2), a3 = G1_DSA(boC, 3);
    longx2 b0 = G1_DSB(boC, 0), b1 = G1_DSB(boC, 1), b2 = G1_DSB(boC, 2), b3 = G1_DSB(boC, 3);
    if (kt + 2 < nKt) {
      G1_STA(wave, kt + 2, boNN); G1_STB(wave, kt + 2, boNN); G1_STB(wave + 8, kt + 2, boNN);
    }
    PRIO1();
    // ksub0 (K 0..31)
    acc[0][0] = MM8(a0[0], b0[0], acc[0][0]); acc[0][1] = MM8(a0[0], b1[0], acc[0][1]);
    acc[0][2] = MM8(a0[0], b2[0], acc[0][2]); acc[0][3] = MM8(a0[0], b3[0], acc[0][3]);
    acc[1][0] = MM8(a1[0], b0[0], acc[1][0]); acc[1][1] = MM8(a1[0], b1[0], acc[1][1]);
    acc[1][2] = MM8(a1[0], b2[0], acc[1][2]); acc[1][3] = MM8(a1[0], b3[0], acc[1][3]);
    acc[2][0] = MM8(a2[0], b0[0], acc[2][0]); acc[2][1] = MM8(a2[0], b1[0], acc[2][1]);
    acc[2][2] = MM8(a2[0], b2[0], acc[2][2]); acc[2][3] = MM8(a2[0], b3[0], acc[2][3]);
    acc[3][0] = MM8(a3[0], b0[0], acc[3][0]); acc[3][1] = MM8(a3[0], b1[0], acc[3][1]);
    acc[3][2] = MM8(a3[0], b2[0], acc[3][2]); acc[3][3] = MM8(a3[0], b3[0], acc[3][3]);
    // ksub1 (K 32..63) — same acc re-touched at distance 16
    acc[0][0] = MM8(a0[1], b0[1], acc[0][0]); acc[0][1] = MM8(a0[1], b1[1], acc[0][1]);
    acc[0][2] = MM8(a0[1], b2[1], acc[0][2]); acc[0][3] = MM8(a0[1], b3[1], acc[0][3]);
    acc[1][0] = MM8(a1[1], b0[1], acc[1][0]); acc[1][1] = MM8(a1[1], b1[1], acc[1][1]);
    acc[1][2] = MM8(a1[1], b2[1], acc[1][2]); acc[1][3] = MM8(a1[1], b3[1], acc[1][3]);
    acc[2][0] = MM8(a2[1], b0[1], acc[2][0]); acc[2][1] = MM8(a2[1], b1[1], acc[2][1]);
    acc[2][2] = MM8(a2[1], b2[1], acc[2][2]); acc[2][3] = MM8(a2[1], b3[1], acc[2][3]);
    acc[3][0] = MM8(a3[1], b0[1], acc[3][0]); acc[3][1] = MM8(a3[1], b1[1], acc[3][1]);
    acc[3][2] = MM8(a3[1], b2[1], acc[3][2]); acc[3][3] = MM8(a3[1], b3[1], acc[3][3]);
    PRIO0();
    if (kt + 2 < nKt) { VM3(); } else if (kt + 1 < nKt) { VM0(); }
    BARRIER();
    int tswap = boC; boC = boN; boN = boNN; boNN = tswap;
  }

  float tmp = *tptr;
  const float tau = log1pf(expf(tmp));
  // C/D layout: col = lane&15, row = (lane>>4)*4 + reg   [measured m89/m91]
  const int crow = g * 4;
  const int rowB = sb * 128 + wm * 64, colB = tb * 256 + wn * 64;
#pragma unroll
  for (int i = 0; i < 4; ++i)
#pragma unroll
    for (int j = 0; j < 4; ++j) {
      const int col = colB + j * 16 + fr;
      const size_t ktile = col >> 5;
      const int c2 = (col >> 3) & 3, co = col & 7;
#pragma unroll
      for (int rr = 0; rr < 4; ++rr) {
        const int row = rowB + i * 16 + crow + rr;
        const int rb = row >> 4, rl = row & 15;
        const int key4 = (rl >> 1) & 3;
        float d2 = fmaxf(2.0f - acc[i][j][rr] * 0.125f, 0.0f);   // acc = 16*dot
        float d = d2 * rsqrtf(fmaxf(d2, 1e-20f));
        float a = __expf(-tau * d);
        act[(((size_t)rb * actKT + ktile) * 16 + rl) * 32 + ((c2 ^ key4) << 3) + co] =
            f32_to_bf16_bits(a);
      }
    }
}

// ---------------- GEMM2: 128x256 bf16, BK=32, t3, 4 waves x (64x128) ----------------
// out[N,C](f32) = act @ pcT^T.  R12 change: 4 waves (256 thr), per-wave 64x128 (2M x 2N)
// -> A and B bytes each read by exactly 2 waves: LDS traffic 48KB/K-tile (was 64KB with
// 8x 64x64 waves).  MFMA becomes the binding pipe (33 us floor).  Mid-barrier + LGKM0
// skeleton RESTORED (R9/R10-verified; R11's 1-barrier hurt gemm2).  Triple buffer,
// 2 blocks/CU (LDS 144KB), 6 stage calls/wave/K-tile -> VM6 gate:
// at the gate, outstanding = kt+2's 6 (newest) + kt+1's 6; VM6 leaves 6 -> kt+1 landed.
// Region proof as R9: stage(kt+2) overwrites tile kt-1's buffer, whose readers drained
// (LGKM0) before the previous end-of-iteration barrier.
__launch_bounds__(256, 2)
__global__ void gemm2_bf16_w4(const ushort_t* __restrict__ A,
                              const ushort_t* __restrict__ B,
                              float* __restrict__ out, int ldc, int ncols,
                              int nKt) {
  __shared__ __align__(16) uchar_t sm[73728];   // 3 x (A 8K + B 16K)
  const int tid = threadIdx.x, lane = tid & 63, wave = tid >> 6;   // 4 waves
  const int wm = wave >> 1, wn = wave & 1;                         // 2M x 2N, 64x128 each
  const int lid = blockIdx.x, xcd = lid & 7, q = lid >> 3;
  const int tb = q & 3, sb = ((q >> 2) << 3) | xcd;   // col-tile 0..3, row-tile 0..127

  f32x4 acc[4][8];
#pragma unroll
  for (int i = 0; i < 4; ++i)
#pragma unroll
    for (int j = 0; j < 8; ++j) acc[i][j] = (f32x4){0.f, 0.f, 0.f, 0.f};

  const uchar_t* Apl = (const uchar_t*)A + (((size_t)(sb * 8) * nKt) << 10) + lane * 16;
  const uchar_t* Bpl = (const uchar_t*)B + (((size_t)(tb * 16) * nKt) << 10) + lane * 16;

  const int fr = lane & 15, g = lane >> 4;
  const int rdoff = fr * 64 + ((g ^ ((fr >> 1) & 3)) << 4);
  const uchar_t* smA = sm + ((wm * 4) << 10) + rdoff;   // wm selects 4 A row-tiles
  const uchar_t* smB = sm + 8192 + ((wn * 8) << 10) + rdoff;  // wn selects 8 B col-tiles

  // stage roles (6 calls/wave/K-tile): wave w stages A {w, w+4}, B {w, w+4, w+8, w+12}
#define W4_STA(r_, T_, bo_) gld_lds16(Apl + ((size_t)((r_) * nKt + (T_)) << 10), \
                                      sm + (bo_) + ((r_) << 10))
#define W4_STB(c_, T_, bo_) gld_lds16(Bpl + ((size_t)((c_) * nKt + (T_)) << 10), \
                                      sm + (bo_) + 8192 + ((c_) << 10))
#define W4_DSA(bo_, i_) (*(const bf16x8*)(smA + (bo_) + ((i_) << 10)))
#define W4_DSB(bo_, j_) (*(const bf16x8*)(smB + (bo_) + ((j_) << 10)))

  // prologue: tile 0 (oldest 6), tile 1 (6); VM6 drains tile 0
  W4_STA(wave, 0, 0); W4_STA(wave + 4, 0, 0);
  W4_STB(wave, 0, 0); W4_STB(wave + 4, 0, 0); W4_STB(wave + 8, 0, 0); W4_STB(wave + 12, 0, 0);
  W4_STA(wave, 1, 24576); W4_STA(wave + 4, 1, 24576);
  W4_STB(wave, 1, 24576); W4_STB(wave + 4, 1, 24576); W4_STB(wave + 8, 1, 24576); W4_STB(wave + 12, 1, 24576);
  VM6(); BARRIER();

  int boC = 0, boN = 24576, boNN = 49152;
  for (int kt = 0; kt < nKt; ++kt) {
    bf16x8 a0 = W4_DSA(boC, 0), a1 = W4_DSA(boC, 1), a2 = W4_DSA(boC, 2), a3 = W4_DSA(boC, 3);
    bf16x8 b0 = W4_DSB(boC, 0), b1 = W4_DSB(boC, 1), b2 = W4_DSB(boC, 2), b3 = W4_DSB(boC, 3);
    bf16x8 b4 = W4_DSB(boC, 4), b5 = W4_DSB(boC, 5), b6 = W4_DSB(boC, 6), b7 = W4_DSB(boC, 7);
    if (kt + 2 < nKt) {
      W4_STA(wave, kt + 2, boNN); W4_STA(wave + 4, kt + 2, boNN);
      W4_STB(wave, kt + 2, boNN); W4_STB(wave + 4, kt + 2, boNN);
      W4_STB(wave + 8, kt + 2, boNN); W4_STB(wave + 12, kt + 2, boNN);
    }
    BARRIER(); LGKM0();
    PRIO1();
    acc[0][0] = MM(a0, b0, acc[0][0]); acc[0][1] = MM(a0, b1, acc[0][1]);
    acc[0][2] = MM(a0, b2, acc[0][2]); acc[0][3] = MM(a0, b3, acc[0][3]);
    acc[0][4] = MM(a0, b4, acc[0][4]); acc[0][5] = MM(a0, b5, acc[0][5]);
    acc[0][6] = MM(a0, b6, acc[0][6]); acc[0][7] = MM(a0, b7, acc[0][7]);
    acc[1][0] = MM(a1, b0, acc[1][0]); acc[1][1] = MM(a1, b1, acc[1][1]);
    acc[1][2] = MM(a1, b2, acc[1][2]); acc[1][3] = MM(a1, b3, acc[1][3]);
    acc[1][4] = MM(a1, b4, acc[1][4]); acc[1][5] = MM(a1, b5, acc[1][5]);
    acc[1][6] = MM(a1, b6, acc[1][6]); acc[1][7] = MM(a1, b7, acc[1][7]);
    acc[2][0] = MM(a2, b0, acc[2][0]); acc[2][1] = MM(a2, b1, acc[2][1]);
    acc[2][2] = MM(a2, b2, acc[2][2]); acc[2][3] = MM(a2, b3, acc[2][3]);
    acc[2][4] = MM(a2, b4, acc[2][4]); acc[2][5] = MM(a2, b5, acc[2][5]);
    acc[2][6] = MM(a2, b6, acc[2][6]); acc[2][7] = MM(a2, b7, acc[2][7]);
    acc[3][0] = MM(a3, b0, acc[3][0]); acc[3][1] = MM(a3, b1, acc[3][1]);
    acc[3][2] = MM(a3, b2, acc[3][2]); acc[3][3] = MM(a3, b3, acc[3][3]);
    acc[3][4] = MM(a3, b4, acc[3][4]); acc[3][5] = MM(a3, b5, acc[3][5]);
    acc[3][6] = MM(a3, b6, acc[3][6]); acc[3][7] = MM(a3, b7, acc[3][7]);
    PRIO0();
    if (kt + 2 < nKt) { VM6(); } else if (kt + 1 < nKt) { VM0(); }
    BARRIER();
    int tswap = boC; boC = boN; boN = boNN; boNN = tswap;
  }

  // epilogue: C/D layout col = lane&15, row = (lane>>4)*4 + reg
  const int crow = g * 4;
  const int rowB = sb * 128 + wm * 64, colB = tb * 256 + wn * 128;
#pragma unroll
  for (int i = 0; i < 4; ++i)
#pragma unroll
    for (int j = 0; j < 8; ++j) {
      const int col = colB + j * 16 + fr;
      if (col < ncols) {
#pragma unroll
        for (int rr = 0; rr < 4; ++rr)
          out[(size_t)(rowB + i * 16 + crow + rr) * ldc + col] = acc[i][j][rr];
      }
    }
}

extern "C" void kernel_launch(void* const* d_in, const int* in_sizes, int n_in,
                              void* d_out, int out_size, void* d_ws, size_t ws_size,
                              hipStream_t stream) {
  const float* h    = (const float*)d_in[0];
  const float* prot = (const float*)d_in[1];
  const float* pc   = (const float*)d_in[2];
  const float* temp = (const float*)d_in[3];
  float* out = (float*)d_out;

  const int D = 768;
  const int N = in_sizes[0] / D;          // 16384
  const int P = in_sizes[1] / D;          // 2048
  const int C = in_sizes[2] / P;          // 1000
  const int CP = (C + 127) & ~127;        // 1024 (padded)

  // workspace layout (16B aligned), all tiled
  char* ws = (char*)d_ws;
  size_t off = 0;
  uchar_t* h8   = (uchar_t*)(ws + off); off += (size_t)N * D;         // 12.6 MB fp8
  uchar_t* p8   = (uchar_t*)(ws + off); off += (size_t)P * D;         //  1.6 MB fp8
  ushort_t* pcT = (ushort_t*)(ws + off); off += (size_t)CP * P * 2;   //  4.2 MB bf16
  ushort_t* act = (ushort_t*)(ws + off); off += (size_t)N * P * 2;    // 67.1 MB bf16
  (void)ws_size;  // total ~85.5 MB

  // single prep dispatch: normalize (fp8 x4, paired-unit tiled) + transpose (bf16, tiled)
  const int normBlocks = (N + P) / 4;                 // 4608
  const int transBlocks = (P / 32) * (CP / 32);       // 2048
  prep<<<normBlocks + transBlocks, 256, 0, stream>>>(
      (const float4*)h, h8, N, (const float4*)prot, p8, P,
      pc, pcT, P, C, normBlocks);

  // GEMM1: act[N,P](bf16 tiled) = epilogue(h8 @ p8^T), fp8, 128x256 BK=64 t3 (1-barrier)
  {
    const int GX = P / 256, GY = N / 128;   // 8, 128 -> 1024 blocks
    gemm1_fp8_t3<<<GX * GY, 512, 0, stream>>>(h8, p8, act, temp, D / 64, P / 32, GX, 3);
  }
  // GEMM2: out[N,C](f32) = act @ pcT^T, bf16, 128x256 BK=32 t3, 4 waves x (64x128)
  {
    const int GX = CP / 256, GY = N / 128;  // 4, 128 -> 512 blocks = 2/CU
    gemm2_bf16_w4<<<GX * GY, 256, 0, stream>>>(act, pcT, out, C, C, P / 32);
  }
}